// Round 2
// baseline (171.906 us; speedup 1.0000x reference)
//
#include <hip/hip_runtime.h>

// Problem constants (match reference setup_inputs)
constexpr int   B = 32, E = 64, H = 128, W = 128, R = 13, D = 32;
constexpr float GAIN = 2.0f, BASELINE = 100.0f;
constexpr int   HALF = R / 2;           // 6
constexpr int   PLANE = H * W;          // 16384

// power v^p for p in 0..3, with 0^0 == 1 (matches jnp broadcasting of **arange(4))
__device__ __forceinline__ float pw(float v, int p) {
    float r = 1.0f;
    if (p >= 1) r = v;
    if (p >= 2) r *= v;
    if (p >= 3) r *= v;
    return r;
}

// JAX advanced-index semantics for .at[].add(mode='drop'):
//   negative indices wrap (+size), then anything still OOB is dropped.
// Given image coord c and patch origin o (o in [-6,121]), return patch index
// in [0,R) or -1. The wrapped candidate c-o-128 covers rows/cols that were
// negative pre-normalization; at most one candidate can be valid.
__device__ __forceinline__ int patch_idx(int c, int o) {
    int p = c - o;
    if (p >= 0 && p < R) return p;
    p = c - o - 128;                    // wrap: original index was p' = c-128-o... i.e. negative
    if (p >= 0 && p < R) return p;
    return -1;
}

__global__ __launch_bounds__(256)
void render_kernel(const float* __restrict__ xyz,      // [B,E,3]
                   const float* __restrict__ n_photons,// [B,E]
                   const float* __restrict__ bg,       // [B,H,W]
                   const float* __restrict__ coeff,    // [D,R,R,4,4,4]
                   float* __restrict__ out)            // [B,E,H,W]
{
    const int be = blockIdx.x;          // 0 .. B*E-1
    const int b  = be >> 6;             // be / E
    const int tid = threadIdx.x;

    __shared__ float s_w[64];           // separable weights pz[a]*py[b]*px[c]
    __shared__ float s_patch[R * R];    // nph-scaled PSF patch

    // --- emitter parameters (broadcast loads; every thread computes redundantly) ---
    const float x = xyz[be * 3 + 0];
    const float y = xyz[be * 3 + 1];
    const float z = xyz[be * 3 + 2];
    const float nph = n_photons[be];

    const float xf = floorf(x), yf = floorf(y);
    const float dx = x - xf,   dy = y - yf;
    float zc = fminf(fmaxf(z, 0.0f), (float)(D - 1) - 1e-6f);
    const float zf = floorf(zc);
    const int   zi = (int)zf;
    const float dz = zc - zf;

    const int r0 = (int)yf - HALF;      // first patch row's image row (may be <0)
    const int c0 = (int)xf - HALF;      // first patch col's image col (may be <0)

    // --- stage 1: 64 separable weights into LDS ---
    if (tid < 64) {
        const int a = tid >> 4;         // dz power
        const int bb = (tid >> 2) & 3;  // dy power
        const int c = tid & 3;          // dx power
        s_w[tid] = pw(dz, a) * pw(dy, bb) * pw(dx, c);
    }
    __syncthreads();

    // --- stage 2: 13x13 patch, one pixel per thread (threads 0..168) ---
    if (tid < R * R) {
        const int prow = tid / R;
        const int pcol = tid - prow * R;
        const float* cp = coeff + (((size_t)zi * R + prow) * R + pcol) * 64;
        float acc = 0.0f;
        #pragma unroll
        for (int k = 0; k < 64; k += 4) {
            const float4 cc = *(const float4*)(cp + k);
            acc += cc.x * s_w[k + 0];
            acc += cc.y * s_w[k + 1];
            acc += cc.z * s_w[k + 2];
            acc += cc.w * s_w[k + 3];
        }
        s_patch[tid] = acc * nph;
    }
    __syncthreads();

    // --- stage 3: stream the whole 128x128 plane, float4 per thread-iter ---
    const float* __restrict__ bgp  = bg  + (size_t)b  * PLANE;
    float*       __restrict__ outp = out + (size_t)be * PLANE;

    #pragma unroll
    for (int i = tid; i < PLANE / 4; i += 256) {
        const int pix = i << 2;
        const int row = pix >> 7;       // / W
        const int col = pix & (W - 1);
        float4 v = *(const float4*)(bgp + pix);

        const int pr = patch_idx(row, r0);
        if (pr >= 0) {
            const float* prow = s_patch + pr * R;
            const int p0 = patch_idx(col + 0, c0);
            const int p1 = patch_idx(col + 1, c0);
            const int p2 = patch_idx(col + 2, c0);
            const int p3 = patch_idx(col + 3, c0);
            if (p0 >= 0) v.x += prow[p0];
            if (p1 >= 0) v.y += prow[p1];
            if (p2 >= 0) v.z += prow[p2];
            if (p3 >= 0) v.w += prow[p3];
        }

        v.x = v.x * GAIN + BASELINE;
        v.y = v.y * GAIN + BASELINE;
        v.z = v.z * GAIN + BASELINE;
        v.w = v.w * GAIN + BASELINE;
        *(float4*)(outp + pix) = v;
    }
}

extern "C" void kernel_launch(void* const* d_in, const int* in_sizes, int n_in,
                              void* d_out, int out_size, void* d_ws, size_t ws_size,
                              hipStream_t stream) {
    const float* xyz       = (const float*)d_in[0];  // [B,E,3]
    const float* n_photons = (const float*)d_in[1];  // [B,E]
    const float* bg        = (const float*)d_in[2];  // [B,H,W]
    const float* coeff     = (const float*)d_in[3];  // [D,R,R,4,4,4]
    float* out = (float*)d_out;                      // [B,E,H,W]

    render_kernel<<<dim3(B * E), dim3(256), 0, stream>>>(xyz, n_photons, bg, coeff, out);
}

// Round 3
// 161.681 us; speedup vs baseline: 1.0632x; 1.0632x over previous
//
#include <hip/hip_runtime.h>

// Problem constants (match reference setup_inputs)
constexpr int   B = 32, E = 64, H = 128, W = 128, R = 13, D = 32;
constexpr float GAIN = 2.0f, BASELINE = 100.0f;
constexpr int   HALF = R / 2;           // 6
constexpr int   PLANE = H * W;          // 16384 floats/plane
constexpr int   PLANE4 = PLANE / 4;     // 4096 float4/plane

// power v^p for p in 0..3, with 0^0 == 1
__device__ __forceinline__ float pw(float v, int p) {
    float r = 1.0f;
    if (p >= 1) r = v;
    if (p >= 2) r *= v;
    if (p >= 3) r *= v;
    return r;
}

// ---------------------------------------------------------------------------
// Kernel A: branch-free background stream.  out[b,e,p] = bg[b,p]*GAIN+BASELINE
// 8192 blocks x 256 threads x 4 float4 = 33.5M floats = 134 MB written.
// ---------------------------------------------------------------------------
__global__ __launch_bounds__(256)
void stream_bg_kernel(const float* __restrict__ bg,   // [B,H,W]
                      float* __restrict__ out)        // [B,E,H,W]
{
    const int tid = threadIdx.x;
    const long long base4 = (long long)blockIdx.x * 1024;   // float4 units
    #pragma unroll
    for (int j = 0; j < 4; ++j) {
        const long long idx4 = base4 + j * 256 + tid;       // global float4 idx
        const int within4 = (int)(idx4 & (PLANE4 - 1));     // float4 within plane
        const int b       = (int)(idx4 >> 18);              // / (E*PLANE4) = 2^18
        const float4 v = *(const float4*)(bg + ((size_t)b << 14) + ((size_t)within4 << 2));
        float4 o;
        o.x = v.x * GAIN + BASELINE;
        o.y = v.y * GAIN + BASELINE;
        o.z = v.z * GAIN + BASELINE;
        o.w = v.w * GAIN + BASELINE;
        *(float4*)(out + (idx4 << 2)) = o;
    }
}

// ---------------------------------------------------------------------------
// Kernel B: per-emitter patch overwrite (runs after A, stream-ordered).
// JAX .at[].add(mode='drop') semantics: negative indices wrap (+size), then
// still-OOB dropped. r0,c0 >= -6 so wrapped index is always >= 122 (valid);
// high side (>=128) is dropped.  Final value written directly:
//   out = (bg + patch)*GAIN + BASELINE   (fp add commutes -> matches ref)
// ---------------------------------------------------------------------------
__global__ __launch_bounds__(256)
void patch_kernel(const float* __restrict__ xyz,       // [B,E,3]
                  const float* __restrict__ n_photons, // [B,E]
                  const float* __restrict__ bg,        // [B,H,W]
                  const float* __restrict__ coeff,     // [D,R,R,4,4,4]
                  float* __restrict__ out)             // [B,E,H,W]
{
    const int be  = blockIdx.x;          // emitter id
    const int b   = be >> 6;             // / E
    const int tid = threadIdx.x;

    __shared__ float s_w[64];            // separable weights pz[a]*py[b]*px[c]

    // emitter parameters (broadcast loads, computed redundantly)
    const float x = xyz[be * 3 + 0];
    const float y = xyz[be * 3 + 1];
    const float z = xyz[be * 3 + 2];
    const float nph = n_photons[be];

    const float xf = floorf(x), yf = floorf(y);
    const float dx = x - xf,   dy = y - yf;
    float zc = fminf(fmaxf(z, 0.0f), (float)(D - 1) - 1e-6f);
    const float zf = floorf(zc);
    const int   zi = (int)zf;
    const float dz = zc - zf;

    const int r0 = (int)yf - HALF;
    const int c0 = (int)xf - HALF;

    if (tid < 64) {
        const int a  = tid >> 4;
        const int bb = (tid >> 2) & 3;
        const int c  = tid & 3;
        s_w[tid] = pw(dz, a) * pw(dy, bb) * pw(dx, c);
    }
    __syncthreads();

    if (tid < R * R) {
        const int pr = tid / R;
        const int pc = tid - pr * R;

        const float* cp = coeff + (((size_t)zi * R + pr) * R + pc) * 64;
        float acc = 0.0f;
        #pragma unroll
        for (int k = 0; k < 64; k += 4) {
            const float4 cc = *(const float4*)(cp + k);
            acc += cc.x * s_w[k + 0];
            acc += cc.y * s_w[k + 1];
            acc += cc.z * s_w[k + 2];
            acc += cc.w * s_w[k + 3];
        }
        const float patch = acc * nph;

        int row = r0 + pr;  if (row < 0) row += H;   // JAX negative-index wrap
        int col = c0 + pc;  if (col < 0) col += W;
        if (row < H && col < W) {                    // high side: dropped
            const size_t ppix = ((size_t)(row << 7)) + col;
            const float  bgv  = bg[((size_t)b << 14) + ppix];
            out[((size_t)be << 14) + ppix] = (bgv + patch) * GAIN + BASELINE;
        }
    }
}

extern "C" void kernel_launch(void* const* d_in, const int* in_sizes, int n_in,
                              void* d_out, int out_size, void* d_ws, size_t ws_size,
                              hipStream_t stream) {
    const float* xyz       = (const float*)d_in[0];  // [B,E,3]
    const float* n_photons = (const float*)d_in[1];  // [B,E]
    const float* bg        = (const float*)d_in[2];  // [B,H,W]
    const float* coeff     = (const float*)d_in[3];  // [D,R,R,4,4,4]
    float* out = (float*)d_out;                      // [B,E,H,W]

    // A: 32*64*16384 floats / (256 thr * 16 floats) = 8192 blocks
    stream_bg_kernel<<<dim3(8192), dim3(256), 0, stream>>>(bg, out);
    // B: one block per emitter; overwrites the <=169 patch pixels per plane
    patch_kernel<<<dim3(B * E), dim3(256), 0, stream>>>(xyz, n_photons, bg, coeff, out);
}